// Round 11
// baseline (570.249 us; speedup 1.0000x reference)
//
#include <hip/hip_runtime.h>
#include <hip/hip_bf16.h>

typedef __attribute__((ext_vector_type(8))) short  short8;
typedef __attribute__((ext_vector_type(4))) float  f32x4;

#define HIDDEN   256
#define NLAYERS  4
#define NPTS     131072
#define PPW      16
#define NWG      (NPTS / PPW)          // 8192
#define NSTATE   5                     // h, g0, g1, gt, S=s0+s1
#define PLANE    40960                 // bytes per state plane (5*8 tiles x 1KB)

// workspace layout (bytes)
#define WS_PARTIALS   0                          // 8192 doubles = 64 KB
#define WS_WHI        65536
#define WPLANE_BYTES  (4 * 16 * 8 * 1024)        // 4 layers x 16 jt x 8 kt x 1KB
#define WS_WLO        (WS_WHI + WPLANE_BYTES)

__device__ __forceinline__ unsigned short f2bf(float f) {
    return __builtin_bit_cast(unsigned short, __float2bfloat16(f));   // HW RNE convert
}
__device__ __forceinline__ float bf2f(unsigned short h) {
    return __uint_as_float(((unsigned)h) << 16);
}
// pack two f32 -> one u32 of 2x bf16 (RNE); emits v_cvt_pk_bf16_f32.
// (__hip_bfloat162 is not trivially copyable -> use memcpy, not bit_cast)
__device__ __forceinline__ unsigned pack2(float a, float b) {
    __hip_bfloat162 h2 = __float22bfloat162_rn(make_float2(a, b));
    unsigned u;
    __builtin_memcpy(&u, &h2, sizeof(u));
    return u;
}
__device__ __forceinline__ float fast_tanh(float z) {
    // tanh(z) = 1 - 2/(exp(2z)+1): exact at both saturations, no NaN
    float e = __expf(2.f * z);
    return 1.f - __fdividef(2.f, e + 1.f);
}

// ---------------- weight prep: split W_h into bf16 hi/lo, fragment-contiguous ----------------
// Fragment (layer, jt, kt): lane l holds W[k][j] for j = jt*16 + (l&15),
// k = kt*32 + (l>>4)*8 + e (e=0..7). Used as MFMA A-operand (rows = j, K = k).
// W stays split (wh + wl products, ~fp32 weight precision); states are bf16.
__global__ void prep_w(const float* __restrict__ Wh,
                       unsigned short* __restrict__ whi, unsigned short* __restrict__ wlo)
{
    int b    = blockIdx.x;               // 512 = 4 layers x 16 jt x 8 kt
    int lay  = b >> 7;
    int jt   = (b >> 3) & 15;
    int kt   = b & 7;
    int lane = threadIdx.x;              // 64
    int j    = jt * 16 + (lane & 15);
    int k0   = kt * 32 + (lane >> 4) * 8;
    const float* W = Wh + (size_t)lay * HIDDEN * HIDDEN;
    int base = ((lay * 16 + jt) * 8 + kt) * 512 + lane * 8;  // ushort units
#pragma unroll
    for (int e = 0; e < 8; ++e) {
        float w = W[(k0 + e) * HIDDEN + j];
        unsigned short h = f2bf(w);
        whi[base + e] = h;
        wlo[base + e] = f2bf(w - bf2f(h));
    }
}

// ---------------- fused PINN kernel: 512 thr (8 waves), 80 KB LDS, 2 WGs/CU ----------------
// Ping-pong bf16 state planes P0/P1 (40 KB each): layer l reads P(l&1), writes P(~l&1);
// ONE barrier per layer (after tanh writes).
// Plane layout: tile (s, kt) at byte (s*8+kt)*1024.
// Element (s, point p, k): byte = (s*8 + (k>>5))*1024 + (((k>>3)&3)*16 + p)*16 + (k&7)*2
// As MFMA B-operand: lane l -> col(point) = l&15, k = kt*32 + (l>>4)*8 + e.
// Wave wid owns j-tiles jt = wid*2, wid*2+1. mfma(W_frag, S_frag) -> D: col = point,
// row j = jt*16 + (lane>>4)*4 + reg  (4 consecutive j per lane -> packed b64 writes).
__global__ __launch_bounds__(512, 4)
void pinn_mfma(const float* __restrict__ X,
               const float* __restrict__ W_in, const float* __restrict__ b_in,
               const float* __restrict__ b_h,  const float* __restrict__ W_out,
               const unsigned short* __restrict__ whi, const unsigned short* __restrict__ wlo,
               double* __restrict__ partials)
{
    extern __shared__ char lds[];
    char*   P0  = lds;                        // 40960 B plane (layers 0,2 read; input writes)
    char*   P1  = lds + PLANE;                // 40960 B plane (layers 1,3 read)
    float*  red = (float*)P1;                 // aliases P1 ch0 tiles (dead in output phase)
    double* sq  = (double*)(P1 + 2048);       // aliases P1 ch0 kt=2 tile: 16 doubles

    const int tid  = threadIdx.x;
    const int lane = tid & 63;
    const int swid = __builtin_amdgcn_readfirstlane(tid >> 6);   // wave id, SGPR
    const int q    = lane >> 4;          // 0..3
    const int p_   = lane & 15;
    const int wg   = blockIdx.x;
    const int pt0  = wg * PPW;

    // ---- input layer -> P0: thread (p = tid&15, jq0 = tid>>4) covers 2 j-quads ----
    {
        const int p   = tid & 15;
        const int jq0 = tid >> 4;                // 0..31
        const float* xp = X + (pt0 + p) * 3;
        const float x0 = xp[0], x1 = xp[1], x2 = xp[2];
#pragma unroll
        for (int i = 0; i < 2; ++i) {
            const int jq = jq0 + 32 * i;         // 0..63
            const int j0 = jq * 4;
            const f32x4 w0 = *(const f32x4*)(W_in + j0);
            const f32x4 w1 = *(const f32x4*)(W_in + HIDDEN + j0);
            const f32x4 w2 = *(const f32x4*)(W_in + 2 * HIDDEN + j0);
            const f32x4 bq = *(const f32x4*)(b_in + j0);
            float o[NSTATE][4];
#pragma unroll
            for (int r = 0; r < 4; ++r) {
                float z  = fmaf(x0, w0[r], fmaf(x1, w1[r], fmaf(x2, w2[r], bq[r])));
                float a  = fast_tanh(z);
                float td = 1.f - a * a;
                float m2 = -2.f * a * td;
                o[0][r] = a; o[1][r] = td * w0[r]; o[2][r] = td * w1[r]; o[3][r] = td * w2[r];
                o[4][r] = m2 * fmaf(w0[r], w0[r], w1[r] * w1[r]);
            }
            const int kt = j0 >> 5, kg = (j0 >> 3) & 3, e0 = j0 & 7;
            const int sub = (kg * 16 + p) * 16 + e0 * 2;
#pragma unroll
            for (int s = 0; s < NSTATE; ++s) {
                uint2 w2v = { pack2(o[s][0], o[s][1]), pack2(o[s][2], o[s][3]) };
                *(uint2*)(P0 + (s * 8 + kt) * 1024 + sub) = w2v;
            }
        }
    }
    __syncthreads();

    // ---- hidden layers: MFMA GEMM, W split (wh + wl), bf16 states, ping-pong planes ----
#pragma unroll 1
    for (int l = 0; l < NLAYERS; ++l) {
        char* SP  = (l & 1) ? P1 : P0;   // read plane
        char* SPn = (l & 1) ? P0 : P1;   // write plane
        const char* sbase = SP + lane * 16;
        const unsigned short* wbh = whi + (l * 16 + swid * 2) * 4096 + lane * 8;
        const unsigned short* wbl = wlo + (l * 16 + swid * 2) * 4096 + lane * 8;

        f32x4 bias[2];
#pragma unroll
        for (int jj = 0; jj < 2; ++jj)
            bias[jj] = *(const f32x4*)(b_h + l * HIDDEN + (swid * 2 + jj) * 16 + q * 4);

        f32x4 acc[2][NSTATE];
#pragma unroll
        for (int jj = 0; jj < 2; ++jj)
#pragma unroll
            for (int mt = 0; mt < NSTATE; ++mt)
                acc[jj][mt] = (f32x4){0.f, 0.f, 0.f, 0.f};

#pragma unroll 2
        for (int kt = 0; kt < 8; ++kt) {
            short8 wh[2], wl[2];
#pragma unroll
            for (int jj = 0; jj < 2; ++jj) {
                wh[jj] = *(const short8*)(wbh + jj * 4096 + kt * 512);
                wl[jj] = *(const short8*)(wbl + jj * 4096 + kt * 512);
            }
            short8 sh_[NSTATE];
#pragma unroll
            for (int mt = 0; mt < NSTATE; ++mt)
                sh_[mt] = *(const short8*)(sbase + (mt * 8 + kt) * 1024);

            __builtin_amdgcn_s_setprio(1);
            // product-major: 10 MFMAs between accumulator reuses
#pragma unroll
            for (int jj = 0; jj < 2; ++jj)
#pragma unroll
                for (int mt = 0; mt < NSTATE; ++mt)
                    acc[jj][mt] = __builtin_amdgcn_mfma_f32_16x16x32_bf16(wh[jj], sh_[mt], acc[jj][mt], 0, 0, 0);
#pragma unroll
            for (int jj = 0; jj < 2; ++jj)
#pragma unroll
                for (int mt = 0; mt < NSTATE; ++mt)
                    acc[jj][mt] = __builtin_amdgcn_mfma_f32_16x16x32_bf16(wl[jj], sh_[mt], acc[jj][mt], 0, 0, 0);
            __builtin_amdgcn_s_setprio(0);
        }

        // NO barrier here: tanh writes go to the other plane (ping-pong kills the WAR)

        // tanh jet chain; lane owns 4 consecutive j per jj -> packed b64 writes
#pragma unroll
        for (int jj = 0; jj < 2; ++jj) {
            const int j0 = (swid * 2 + jj) * 16 + q * 4;
            const int kt = j0 >> 5, kg = (j0 >> 3) & 3, e0 = j0 & 7;
            const int sub = (kg * 16 + p_) * 16 + e0 * 2;
            float o[NSTATE][4];
#pragma unroll
            for (int r = 0; r < 4; ++r) {
                float z0 = acc[jj][0][r] + bias[jj][r];
                float z1 = acc[jj][1][r], z2 = acc[jj][2][r];
                float z3 = acc[jj][3][r], zS = acc[jj][4][r];
                float a  = fast_tanh(z0);
                float td = 1.f - a * a;
                float m2 = -2.f * a * td;
                o[0][r] = a; o[1][r] = td * z1; o[2][r] = td * z2; o[3][r] = td * z3;
                o[4][r] = fmaf(td, zS, m2 * fmaf(z1, z1, z2 * z2));
            }
            const int sLo = (l < NLAYERS - 1) ? 0 : 3;   // last layer: only gt,S live
#pragma unroll
            for (int s = 0; s < NSTATE; ++s) {
                if (s < sLo) continue;
                uint2 w2v = { pack2(o[s][0], o[s][1]), pack2(o[s][2], o[s][3]) };
                *(uint2*)(SPn + (s * 8 + kt) * 1024 + sub) = w2v;
            }
        }
        __syncthreads();   // RAW: next layer's GEMM (or output phase) reads SPn
    }

    // ---- output: residual_p = sum_j W_out[j]*(gt - S); reads P0 ch 3,4 only ----
    {
        const int p   = tid & 15;
        const int jq0 = tid >> 4;          // 0..31
        float sum = 0.f;
#pragma unroll
        for (int i = 0; i < 2; ++i) {
            const int jq = jq0 + 32 * i, j0 = jq * 4;
            const int kt = j0 >> 5, kg = (j0 >> 3) & 3, e0 = j0 & 7;
            const int sub = (kg * 16 + p) * 16 + e0 * 2;
            uint2 gv = *(uint2*)(P0 + (3 * 8 + kt) * 1024 + sub);
            uint2 Sv = *(uint2*)(P0 + (4 * 8 + kt) * 1024 + sub);
            f32x4 wo = *(const f32x4*)(W_out + j0);
            sum = fmaf(wo[0], bf2f((unsigned short)(gv.x & 0xFFFF)) - bf2f((unsigned short)(Sv.x & 0xFFFF)), sum);
            sum = fmaf(wo[1], bf2f((unsigned short)(gv.x >> 16))    - bf2f((unsigned short)(Sv.x >> 16)),    sum);
            sum = fmaf(wo[2], bf2f((unsigned short)(gv.y & 0xFFFF)) - bf2f((unsigned short)(Sv.y & 0xFFFF)), sum);
            sum = fmaf(wo[3], bf2f((unsigned short)(gv.y >> 16))    - bf2f((unsigned short)(Sv.y >> 16)),    sum);
        }
        red[jq0 * 16 + p] = sum;   // red aliases P1 (fully dead after layer 3)
    }
    __syncthreads();
    if (tid < PPW) {
        float s = 0.f;
        for (int g = 0; g < 32; ++g) s += red[g * 16 + tid];   // fixed order
        double d = (double)s;
        sq[tid] = d * d;
    }
    __syncthreads();
    if (tid == 0) {
        double tot = 0.0;
        for (int p = 0; p < PPW; ++p) tot += sq[p];            // fixed order
        partials[wg] = tot;
    }
}

__global__ void pinn_reduce_kernel(const double* __restrict__ partials, float* __restrict__ out)
{
    __shared__ double sh[256];
    double t = 0.0;
    for (int i = 0; i < NWG / 256; ++i) t += partials[threadIdx.x * (NWG / 256) + i]; // fixed order
    sh[threadIdx.x] = t;
    __syncthreads();
    for (int ofs = 128; ofs > 0; ofs >>= 1) {
        if ((int)threadIdx.x < ofs) sh[threadIdx.x] += sh[threadIdx.x + ofs];
        __syncthreads();
    }
    if (threadIdx.x == 0) {
        out[0] = (float)(sh[0] / (double)NPTS);  // pde_loss
        out[1] = 0.f;                            // ode_loss
    }
}

extern "C" void kernel_launch(void* const* d_in, const int* in_sizes, int n_in,
                              void* d_out, int out_size, void* d_ws, size_t ws_size,
                              hipStream_t stream)
{
    const float* X     = (const float*)d_in[0];
    const float* W_in  = (const float*)d_in[1];
    const float* b_in  = (const float*)d_in[2];
    const float* W_h   = (const float*)d_in[3];
    const float* b_h   = (const float*)d_in[4];
    const float* W_out = (const float*)d_in[5];
    // d_in[6] = b_out: constant output offset, zero derivative -> unused

    double*         partials = (double*)((char*)d_ws + WS_PARTIALS);
    unsigned short* whi      = (unsigned short*)((char*)d_ws + WS_WHI);
    unsigned short* wlo      = (unsigned short*)((char*)d_ws + WS_WLO);
    float*          out      = (float*)d_out;

    const size_t lds_bytes = 2 * PLANE;  // 81920 B -> 2 WGs/CU
    (void)hipFuncSetAttribute((const void*)pinn_mfma,
                              hipFuncAttributeMaxDynamicSharedMemorySize, (int)lds_bytes);

    hipLaunchKernelGGL(prep_w, dim3(512), dim3(64), 0, stream, W_h, whi, wlo);
    hipLaunchKernelGGL(pinn_mfma, dim3(NWG), dim3(512), lds_bytes, stream,
                       X, W_in, b_in, b_h, W_out, whi, wlo, partials);
    hipLaunchKernelGGL(pinn_reduce_kernel, dim3(1), dim3(256), 0, stream,
                       partials, out);
}

// Round 12
// 567.104 us; speedup vs baseline: 1.0055x; 1.0055x over previous
//
#include <hip/hip_runtime.h>
#include <hip/hip_bf16.h>

typedef __attribute__((ext_vector_type(8)))  short short8;
typedef __attribute__((ext_vector_type(4)))  float f32x4;
typedef __attribute__((ext_vector_type(16))) float f32x16;

#define HIDDEN   256
#define NLAYERS  4
#define NPTS     131072
#define PPW      32
#define NWG      (NPTS / PPW)          // 4096
#define NSTATE   5                     // h, g0, g1, gt, S=s0+s1
#define PLANE    81920                 // bytes: 5 states x 16 k-tiles x 1KB

// workspace layout (bytes)
#define WS_PARTIALS   0                          // 4096 doubles = 32 KB
#define WS_WHI        65536
#define WPLANE_BYTES  (4 * 8 * 16 * 1024)        // 4 layers x 8 jt x 16 kt x 1KB = 512 KB
#define WS_WLO        (WS_WHI + WPLANE_BYTES)

__device__ __forceinline__ unsigned short f2bf(float f) {
    return __builtin_bit_cast(unsigned short, __float2bfloat16(f));   // HW RNE convert
}
__device__ __forceinline__ float bf2f(unsigned short h) {
    return __uint_as_float(((unsigned)h) << 16);
}
// pack two f32 -> one u32 of 2x bf16 (RNE); __hip_bfloat162 isn't trivially copyable
__device__ __forceinline__ unsigned pack2(float a, float b) {
    __hip_bfloat162 h2 = __float22bfloat162_rn(make_float2(a, b));
    unsigned u;
    __builtin_memcpy(&u, &h2, sizeof(u));
    return u;
}
__device__ __forceinline__ float fast_tanh(float z) {
    // tanh(z) = 1 - 2/(exp(2z)+1): exact at both saturations, no NaN
    float e = __expf(2.f * z);
    return 1.f - __fdividef(2.f, e + 1.f);
}

// ---------------- weight prep: split W_h into bf16 hi/lo, 32x32x16-A fragments ----------------
// Fragment (layer, jt, kt): lane l holds W[k][j] for j = jt*32 + (l&31),
// k = kt*16 + (l>>5)*8 + e (e=0..7). 1 KB per fragment.
__global__ void prep_w(const float* __restrict__ Wh,
                       unsigned short* __restrict__ whi, unsigned short* __restrict__ wlo)
{
    int b    = blockIdx.x;               // 512 = 4 layers x 8 jt x 16 kt
    int lay  = b >> 7;
    int jt   = (b >> 4) & 7;
    int kt   = b & 15;
    int lane = threadIdx.x;              // 64
    int j    = jt * 32 + (lane & 31);
    int k0   = kt * 16 + (lane >> 5) * 8;
    const float* W = Wh + lay * 65536;
    int base = ((lay * 8 + jt) * 16 + kt) * 512 + lane * 8;  // ushort units
#pragma unroll
    for (int e = 0; e < 8; ++e) {
        float w = W[(k0 + e) * HIDDEN + j];
        unsigned short h = f2bf(w);
        whi[base + e] = h;
        wlo[base + e] = f2bf(w - bf2f(h));
    }
}

// ---------------- fused PINN kernel: 512 thr (8 waves), 80 KB LDS, 2 WGs/CU ----------------
// Single in-place bf16 state plane, 32x32x16 MFMA:
//   tile (s, kt) at byte (s*16+kt)*1024 (kt = k>>4, 16 tiles/state).
//   element (s, point p, k): byte = (s*16+(k>>4))*1024 + (((k>>3)&1)*32 + p)*16 + (k&7)*2
//   B-operand: lane l -> col(point) = l&31, k = kt*16 + (l>>5)*8 + e.
// Wave wid owns j-tile jt = wid (32 j rows). mfma(W_frag, S_frag) -> D: col = point,
//   row j = jt*32 + 8*(reg>>2) + 4*(lane>>5) + (reg&3)  -> 4 consecutive j per reg-quad.
// Two barriers per layer (in-place plane: read->WAR->write).
__global__ __launch_bounds__(512, 4)
void pinn_mfma(const float* __restrict__ X,
               const float* __restrict__ W_in, const float* __restrict__ b_in,
               const float* __restrict__ b_h,  const float* __restrict__ W_out,
               const unsigned short* __restrict__ whi, const unsigned short* __restrict__ wlo,
               double* __restrict__ partials)
{
    extern __shared__ char lds[];
    float*  red = (float*)lds;                // aliases s=0 tiles 0..1 (dead in output phase)
    double* sq  = (double*)(lds + 2048);      // aliases s=0 tile 2: 32 doubles

    const int tid  = threadIdx.x;
    const int lane = tid & 63;
    const int swid = __builtin_amdgcn_readfirstlane(tid >> 6);   // wave id = j-tile, SGPR
    const int h    = lane >> 5;          // k-half / row-half selector
    const int wg   = blockIdx.x;
    const int pt0  = wg * PPW;

    // ---- input layer: thread (p = tid&31, jseg = tid>>5) covers 16 j (4 quads) ----
    {
        const int p    = tid & 31;
        const int jseg = tid >> 5;               // 0..15
        const float* xp = X + (pt0 + p) * 3;
        const float x0 = xp[0], x1 = xp[1], x2 = xp[2];
#pragma unroll
        for (int qq = 0; qq < 4; ++qq) {
            const int j0 = jseg * 16 + qq * 4;
            const f32x4 w0 = *(const f32x4*)(W_in + j0);
            const f32x4 w1 = *(const f32x4*)(W_in + HIDDEN + j0);
            const f32x4 w2 = *(const f32x4*)(W_in + 2 * HIDDEN + j0);
            const f32x4 bq = *(const f32x4*)(b_in + j0);
            float o[NSTATE][4];
#pragma unroll
            for (int r = 0; r < 4; ++r) {
                float z  = fmaf(x0, w0[r], fmaf(x1, w1[r], fmaf(x2, w2[r], bq[r])));
                float a  = fast_tanh(z);
                float td = 1.f - a * a;
                float m2 = -2.f * a * td;
                o[0][r] = a; o[1][r] = td * w0[r]; o[2][r] = td * w1[r]; o[3][r] = td * w2[r];
                o[4][r] = m2 * fmaf(w0[r], w0[r], w1[r] * w1[r]);
            }
            const int sub = (((j0 >> 3) & 1) * 32 + p) * 16 + (j0 & 7) * 2;
#pragma unroll
            for (int s = 0; s < NSTATE; ++s) {
                uint2 wv = { pack2(o[s][0], o[s][1]), pack2(o[s][2], o[s][3]) };
                *(uint2*)(lds + (s * 16 + (j0 >> 4)) * 1024 + sub) = wv;
            }
        }
    }
    __syncthreads();

    // ---- hidden layers: 32x32x16 MFMA, W split (wh + wl), bf16 states, in-place ----
#pragma unroll 1
    for (int l = 0; l < NLAYERS; ++l) {
        const unsigned short* wbh = whi + ((l * 8 + swid) * 16) * 512 + lane * 8;
        const unsigned short* wbl = wlo + ((l * 8 + swid) * 16) * 512 + lane * 8;
        const char* sbase = lds + lane * 16;

        f32x16 acc[NSTATE];
#pragma unroll
        for (int s = 0; s < NSTATE; ++s)
            acc[s] = (f32x16){0.f,0.f,0.f,0.f,0.f,0.f,0.f,0.f,0.f,0.f,0.f,0.f,0.f,0.f,0.f,0.f};

#pragma unroll 1
        for (int kt = 0; kt < 16; ++kt) {
            short8 wh = *(const short8*)(wbh + kt * 512);
            short8 wl = *(const short8*)(wbl + kt * 512);
            short8 sh_[NSTATE];
#pragma unroll
            for (int s = 0; s < NSTATE; ++s)
                sh_[s] = *(const short8*)(sbase + (s * 16 + kt) * 1024);

            __builtin_amdgcn_s_setprio(1);
#pragma unroll
            for (int s = 0; s < NSTATE; ++s)
                acc[s] = __builtin_amdgcn_mfma_f32_32x32x16_bf16(wh, sh_[s], acc[s], 0, 0, 0);
#pragma unroll
            for (int s = 0; s < NSTATE; ++s)
                acc[s] = __builtin_amdgcn_mfma_f32_32x32x16_bf16(wl, sh_[s], acc[s], 0, 0, 0);
            __builtin_amdgcn_s_setprio(0);
        }

        __syncthreads();   // all GEMM reads done before in-place overwrite

        // tanh jet chain; reg-quad rq -> 4 consecutive j; packed b64 writes
#pragma unroll
        for (int rq = 0; rq < 4; ++rq) {
            const int j0 = swid * 32 + 8 * rq + 4 * h;
            const f32x4 bq = *(const f32x4*)(b_h + l * HIDDEN + j0);
            float o[NSTATE][4];
#pragma unroll
            for (int rr = 0; rr < 4; ++rr) {
                const int r = rq * 4 + rr;
                float z0 = acc[0][r] + bq[rr];
                float z1 = acc[1][r], z2 = acc[2][r];
                float z3 = acc[3][r], zS = acc[4][r];
                float a  = fast_tanh(z0);
                float td = 1.f - a * a;
                float m2 = -2.f * a * td;
                o[0][rr] = a; o[1][rr] = td * z1; o[2][rr] = td * z2; o[3][rr] = td * z3;
                o[4][rr] = fmaf(td, zS, m2 * fmaf(z1, z1, z2 * z2));
            }
            // write address: tile (s, j0>>4), lane slot ((rq&1)*32 + (lane&31)), e = 4h
            const int sub = ((rq & 1) * 32 + (lane & 31)) * 16 + 4 * h * 2;
            const int ktj = swid * 2 + (rq >> 1);
            const int sLo = (l < NLAYERS - 1) ? 0 : 3;   // last layer: only gt,S live
#pragma unroll
            for (int s = 0; s < NSTATE; ++s) {
                if (s < sLo) continue;
                uint2 wv = { pack2(o[s][0], o[s][1]), pack2(o[s][2], o[s][3]) };
                *(uint2*)(lds + (s * 16 + ktj) * 1024 + sub) = wv;
            }
        }
        __syncthreads();   // writes visible before next layer's reads
    }

    // ---- output: residual_p = sum_j W_out[j]*(gt - S); reads s=3,4 tiles only ----
    {
        const int p    = tid & 31;
        const int jseg = tid >> 5;          // 0..15
        float sum = 0.f;
#pragma unroll
        for (int qq = 0; qq < 4; ++qq) {
            const int j0  = jseg * 16 + qq * 4;
            const int sub = (((j0 >> 3) & 1) * 32 + p) * 16 + (j0 & 7) * 2;
            uint2 gv = *(uint2*)(lds + (3 * 16 + (j0 >> 4)) * 1024 + sub);
            uint2 Sv = *(uint2*)(lds + (4 * 16 + (j0 >> 4)) * 1024 + sub);
            f32x4 wo = *(const f32x4*)(W_out + j0);
            sum = fmaf(wo[0], bf2f((unsigned short)(gv.x & 0xFFFF)) - bf2f((unsigned short)(Sv.x & 0xFFFF)), sum);
            sum = fmaf(wo[1], bf2f((unsigned short)(gv.x >> 16))    - bf2f((unsigned short)(Sv.x >> 16)),    sum);
            sum = fmaf(wo[2], bf2f((unsigned short)(gv.y & 0xFFFF)) - bf2f((unsigned short)(Sv.y & 0xFFFF)), sum);
            sum = fmaf(wo[3], bf2f((unsigned short)(gv.y >> 16))    - bf2f((unsigned short)(Sv.y >> 16)),    sum);
        }
        __syncthreads();                    // all s=3,4 reads before red overwrites s=0
        red[jseg * 32 + p] = sum;           // red aliases s=0 tiles: disjoint from s=3,4
    }
    __syncthreads();
    if (tid < PPW) {
        float s = 0.f;
        for (int g = 0; g < 16; ++g) s += red[g * 32 + tid];   // fixed order
        double d = (double)s;
        sq[tid] = d * d;
    }
    __syncthreads();
    if (tid == 0) {
        double tot = 0.0;
        for (int p = 0; p < PPW; ++p) tot += sq[p];            // fixed order
        partials[wg] = tot;
    }
}

__global__ void pinn_reduce_kernel(const double* __restrict__ partials, float* __restrict__ out)
{
    __shared__ double sh[256];
    double t = 0.0;
    for (int i = 0; i < NWG / 256; ++i) t += partials[threadIdx.x * (NWG / 256) + i]; // fixed order
    sh[threadIdx.x] = t;
    __syncthreads();
    for (int ofs = 128; ofs > 0; ofs >>= 1) {
        if ((int)threadIdx.x < ofs) sh[threadIdx.x] += sh[threadIdx.x + ofs];
        __syncthreads();
    }
    if (threadIdx.x == 0) {
        out[0] = (float)(sh[0] / (double)NPTS);  // pde_loss
        out[1] = 0.f;                            // ode_loss
    }
}

extern "C" void kernel_launch(void* const* d_in, const int* in_sizes, int n_in,
                              void* d_out, int out_size, void* d_ws, size_t ws_size,
                              hipStream_t stream)
{
    const float* X     = (const float*)d_in[0];
    const float* W_in  = (const float*)d_in[1];
    const float* b_in  = (const float*)d_in[2];
    const float* W_h   = (const float*)d_in[3];
    const float* b_h   = (const float*)d_in[4];
    const float* W_out = (const float*)d_in[5];
    // d_in[6] = b_out: constant output offset, zero derivative -> unused

    double*         partials = (double*)((char*)d_ws + WS_PARTIALS);
    unsigned short* whi      = (unsigned short*)((char*)d_ws + WS_WHI);
    unsigned short* wlo      = (unsigned short*)((char*)d_ws + WS_WLO);
    float*          out      = (float*)d_out;

    const size_t lds_bytes = PLANE;      // 81920 B -> 2 WGs/CU
    (void)hipFuncSetAttribute((const void*)pinn_mfma,
                              hipFuncAttributeMaxDynamicSharedMemorySize, (int)lds_bytes);

    hipLaunchKernelGGL(prep_w, dim3(512), dim3(64), 0, stream, W_h, whi, wlo);
    hipLaunchKernelGGL(pinn_mfma, dim3(NWG), dim3(512), lds_bytes, stream,
                       X, W_in, b_in, b_h, W_out, whi, wlo, partials);
    hipLaunchKernelGGL(pinn_reduce_kernel, dim3(1), dim3(256), 0, stream,
                       partials, out);
}

// Round 13
// 368.939 us; speedup vs baseline: 1.5456x; 1.5371x over previous
//
#include <hip/hip_runtime.h>
#include <hip/hip_bf16.h>

typedef __attribute__((ext_vector_type(8))) short  short8;
typedef __attribute__((ext_vector_type(4))) float  f32x4;

#define HIDDEN   256
#define NLAYERS  4
#define NPTS     131072
#define PPW      16
#define NWG      (NPTS / PPW)          // 8192
#define NSTATE   5                     // h, g0, g1, gt, S=s0+s1
#define PLANE    40960                 // bytes per state plane (5*8 tiles x 1KB)

// workspace layout (bytes)
#define WS_PARTIALS   0                          // 8192 doubles = 64 KB
#define WS_WHI        65536                      // 512 KB bf16 W fragments

__device__ __forceinline__ unsigned short f2bf(float f) {
    return __builtin_bit_cast(unsigned short, __float2bfloat16(f));   // HW RNE convert
}
__device__ __forceinline__ float bf2f(unsigned short h) {
    return __uint_as_float(((unsigned)h) << 16);
}
// pack two f32 -> one u32 of 2x bf16 (RNE); __hip_bfloat162 isn't trivially copyable
__device__ __forceinline__ unsigned pack2(float a, float b) {
    __hip_bfloat162 h2 = __float22bfloat162_rn(make_float2(a, b));
    unsigned u;
    __builtin_memcpy(&u, &h2, sizeof(u));
    return u;
}
__device__ __forceinline__ float fast_tanh(float z) {
    // tanh(z) = 1 - 2/(exp(2z)+1): exact at both saturations, no NaN
    float e = __expf(2.f * z);
    return 1.f - __fdividef(2.f, e + 1.f);
}

// ---------------- weight prep: W_h -> bf16, fragment-contiguous ----------------
// Fragment (layer, jt, kt): lane l holds W[k][j] for j = jt*16 + (l&15),
// k = kt*32 + (l>>4)*8 + e (e=0..7). Used as MFMA A-operand (rows = j, K = k).
__global__ void prep_w(const float* __restrict__ Wh, unsigned short* __restrict__ whi)
{
    int b    = blockIdx.x;               // 512 = 4 layers x 16 jt x 8 kt
    int lay  = b >> 7;
    int jt   = (b >> 3) & 15;
    int kt   = b & 7;
    int lane = threadIdx.x;              // 64
    int j    = jt * 16 + (lane & 15);
    int k0   = kt * 32 + (lane >> 4) * 8;
    const float* W = Wh + lay * 65536;
    int base = ((lay * 16 + jt) * 8 + kt) * 512 + lane * 8;  // ushort units
#pragma unroll
    for (int e = 0; e < 8; ++e)
        whi[base + e] = f2bf(W[(k0 + e) * HIDDEN + j]);
}

// ---------------- fused PINN kernel: 512 thr (8 waves), 80 KB LDS, 2 WGs/CU ----------------
// Ping-pong bf16 state planes P0/P1 (40 KB each): layer l reads P(l&1), writes P(~l&1);
// ONE barrier per layer (after tanh writes).
// Plane layout: tile (s, kt) at byte (s*8+kt)*1024.
// Element (s, point p, k): byte = (s*8 + (k>>5))*1024 + (((k>>3)&3)*16 + p)*16 + (k&7)*2
// As MFMA B-operand: lane l -> col(point) = l&15, k = kt*32 + (l>>4)*8 + e.
// Wave wid owns j-tiles jt = wid*2, wid*2+1. mfma(W_frag, S_frag) -> D: col = point,
// row j = jt*16 + (lane>>4)*4 + reg  (4 consecutive j per lane -> packed b64 writes).
__global__ __launch_bounds__(512, 4)
void pinn_mfma(const float* __restrict__ X,
               const float* __restrict__ W_in, const float* __restrict__ b_in,
               const float* __restrict__ b_h,  const float* __restrict__ W_out,
               const unsigned short* __restrict__ whi,
               double* __restrict__ partials)
{
    extern __shared__ char lds[];
    char*   P0  = lds;                        // 40960 B plane (layers 0,2 read; input writes)
    char*   P1  = lds + PLANE;                // 40960 B plane (layers 1,3 read)
    float*  red = (float*)P1;                 // aliases P1 ch0 tiles (dead in output phase)
    double* sq  = (double*)(P1 + 2048);       // aliases P1 ch0 kt=2 tile: 16 doubles

    const int tid  = threadIdx.x;
    const int lane = tid & 63;
    const int swid = __builtin_amdgcn_readfirstlane(tid >> 6);   // wave id, SGPR
    const int q    = lane >> 4;          // 0..3
    const int p_   = lane & 15;
    const int wg   = blockIdx.x;
    const int pt0  = wg * PPW;

    // ---- input layer -> P0: thread (p = tid&15, jq0 = tid>>4) covers 2 j-quads ----
    {
        const int p   = tid & 15;
        const int jq0 = tid >> 4;                // 0..31
        const float* xp = X + (pt0 + p) * 3;
        const float x0 = xp[0], x1 = xp[1], x2 = xp[2];
#pragma unroll
        for (int i = 0; i < 2; ++i) {
            const int jq = jq0 + 32 * i;         // 0..63
            const int j0 = jq * 4;
            const f32x4 w0 = *(const f32x4*)(W_in + j0);
            const f32x4 w1 = *(const f32x4*)(W_in + HIDDEN + j0);
            const f32x4 w2 = *(const f32x4*)(W_in + 2 * HIDDEN + j0);
            const f32x4 bq = *(const f32x4*)(b_in + j0);
            float o[NSTATE][4];
#pragma unroll
            for (int r = 0; r < 4; ++r) {
                float z  = fmaf(x0, w0[r], fmaf(x1, w1[r], fmaf(x2, w2[r], bq[r])));
                float a  = fast_tanh(z);
                float td = 1.f - a * a;
                float m2 = -2.f * a * td;
                o[0][r] = a; o[1][r] = td * w0[r]; o[2][r] = td * w1[r]; o[3][r] = td * w2[r];
                o[4][r] = m2 * fmaf(w0[r], w0[r], w1[r] * w1[r]);
            }
            const int kt = j0 >> 5, kg = (j0 >> 3) & 3, e0 = j0 & 7;
            const int sub = (kg * 16 + p) * 16 + e0 * 2;
#pragma unroll
            for (int s = 0; s < NSTATE; ++s) {
                uint2 w2v = { pack2(o[s][0], o[s][1]), pack2(o[s][2], o[s][3]) };
                *(uint2*)(P0 + (s * 8 + kt) * 1024 + sub) = w2v;
            }
        }
    }
    __syncthreads();

    // ---- hidden layers: single-product bf16 MFMA GEMM, ping-pong planes ----
#pragma unroll 1
    for (int l = 0; l < NLAYERS; ++l) {
        char* SP  = (l & 1) ? P1 : P0;   // read plane
        char* SPn = (l & 1) ? P0 : P1;   // write plane
        const char* sbase = SP + lane * 16;
        const unsigned short* wbh = whi + (l * 16 + swid * 2) * 4096 + lane * 8;

        f32x4 bias[2];
#pragma unroll
        for (int jj = 0; jj < 2; ++jj)
            bias[jj] = *(const f32x4*)(b_h + l * HIDDEN + (swid * 2 + jj) * 16 + q * 4);

        f32x4 acc[2][NSTATE];
#pragma unroll
        for (int jj = 0; jj < 2; ++jj)
#pragma unroll
            for (int mt = 0; mt < NSTATE; ++mt)
                acc[jj][mt] = (f32x4){0.f, 0.f, 0.f, 0.f};

#pragma unroll 2
        for (int kt = 0; kt < 8; ++kt) {
            short8 wh[2];
#pragma unroll
            for (int jj = 0; jj < 2; ++jj)
                wh[jj] = *(const short8*)(wbh + jj * 4096 + kt * 512);
            short8 sh_[NSTATE];
#pragma unroll
            for (int mt = 0; mt < NSTATE; ++mt)
                sh_[mt] = *(const short8*)(sbase + (mt * 8 + kt) * 1024);

            __builtin_amdgcn_s_setprio(1);
#pragma unroll
            for (int jj = 0; jj < 2; ++jj)
#pragma unroll
                for (int mt = 0; mt < NSTATE; ++mt)
                    acc[jj][mt] = __builtin_amdgcn_mfma_f32_16x16x32_bf16(wh[jj], sh_[mt], acc[jj][mt], 0, 0, 0);
            __builtin_amdgcn_s_setprio(0);
        }

        // NO barrier here: tanh writes go to the other plane (ping-pong kills the WAR)

        // tanh jet chain; lane owns 4 consecutive j per jj -> packed b64 writes
#pragma unroll
        for (int jj = 0; jj < 2; ++jj) {
            const int j0 = (swid * 2 + jj) * 16 + q * 4;
            const int kt = j0 >> 5, kg = (j0 >> 3) & 3, e0 = j0 & 7;
            const int sub = (kg * 16 + p_) * 16 + e0 * 2;
            float o[NSTATE][4];
#pragma unroll
            for (int r = 0; r < 4; ++r) {
                float z0 = acc[jj][0][r] + bias[jj][r];
                float z1 = acc[jj][1][r], z2 = acc[jj][2][r];
                float z3 = acc[jj][3][r], zS = acc[jj][4][r];
                float a  = fast_tanh(z0);
                float td = 1.f - a * a;
                float m2 = -2.f * a * td;
                o[0][r] = a; o[1][r] = td * z1; o[2][r] = td * z2; o[3][r] = td * z3;
                o[4][r] = fmaf(td, zS, m2 * fmaf(z1, z1, z2 * z2));
            }
            const int sLo = (l < NLAYERS - 1) ? 0 : 3;   // last layer: only gt,S live
#pragma unroll
            for (int s = 0; s < NSTATE; ++s) {
                if (s < sLo) continue;
                uint2 w2v = { pack2(o[s][0], o[s][1]), pack2(o[s][2], o[s][3]) };
                *(uint2*)(SPn + (s * 8 + kt) * 1024 + sub) = w2v;
            }
        }
        __syncthreads();   // RAW: next layer's GEMM (or output phase) reads SPn
    }

    // ---- output: residual_p = sum_j W_out[j]*(gt - S); reads P0 ch 3,4 only ----
    {
        const int p   = tid & 15;
        const int jq0 = tid >> 4;          // 0..31
        float sum = 0.f;
#pragma unroll
        for (int i = 0; i < 2; ++i) {
            const int jq = jq0 + 32 * i, j0 = jq * 4;
            const int kt = j0 >> 5, kg = (j0 >> 3) & 3, e0 = j0 & 7;
            const int sub = (kg * 16 + p) * 16 + e0 * 2;
            uint2 gv = *(uint2*)(P0 + (3 * 8 + kt) * 1024 + sub);
            uint2 Sv = *(uint2*)(P0 + (4 * 8 + kt) * 1024 + sub);
            f32x4 wo = *(const f32x4*)(W_out + j0);
            sum = fmaf(wo[0], bf2f((unsigned short)(gv.x & 0xFFFF)) - bf2f((unsigned short)(Sv.x & 0xFFFF)), sum);
            sum = fmaf(wo[1], bf2f((unsigned short)(gv.x >> 16))    - bf2f((unsigned short)(Sv.x >> 16)),    sum);
            sum = fmaf(wo[2], bf2f((unsigned short)(gv.y & 0xFFFF)) - bf2f((unsigned short)(Sv.y & 0xFFFF)), sum);
            sum = fmaf(wo[3], bf2f((unsigned short)(gv.y >> 16))    - bf2f((unsigned short)(Sv.y >> 16)),    sum);
        }
        red[jq0 * 16 + p] = sum;   // red aliases P1 (fully dead after layer 3)
    }
    __syncthreads();
    if (tid < PPW) {
        float s = 0.f;
        for (int g = 0; g < 32; ++g) s += red[g * 16 + tid];   // fixed order
        double d = (double)s;
        sq[tid] = d * d;
    }
    __syncthreads();
    if (tid == 0) {
        double tot = 0.0;
        for (int p = 0; p < PPW; ++p) tot += sq[p];            // fixed order
        partials[wg] = tot;
    }
}

__global__ void pinn_reduce_kernel(const double* __restrict__ partials, float* __restrict__ out)
{
    __shared__ double sh[256];
    double t = 0.0;
    for (int i = 0; i < NWG / 256; ++i) t += partials[threadIdx.x * (NWG / 256) + i]; // fixed order
    sh[threadIdx.x] = t;
    __syncthreads();
    for (int ofs = 128; ofs > 0; ofs >>= 1) {
        if ((int)threadIdx.x < ofs) sh[threadIdx.x] += sh[threadIdx.x + ofs];
        __syncthreads();
    }
    if (threadIdx.x == 0) {
        out[0] = (float)(sh[0] / (double)NPTS);  // pde_loss
        out[1] = 0.f;                            // ode_loss
    }
}

extern "C" void kernel_launch(void* const* d_in, const int* in_sizes, int n_in,
                              void* d_out, int out_size, void* d_ws, size_t ws_size,
                              hipStream_t stream)
{
    const float* X     = (const float*)d_in[0];
    const float* W_in  = (const float*)d_in[1];
    const float* b_in  = (const float*)d_in[2];
    const float* W_h   = (const float*)d_in[3];
    const float* b_h   = (const float*)d_in[4];
    const float* W_out = (const float*)d_in[5];
    // d_in[6] = b_out: constant output offset, zero derivative -> unused

    double*         partials = (double*)((char*)d_ws + WS_PARTIALS);
    unsigned short* whi      = (unsigned short*)((char*)d_ws + WS_WHI);
    float*          out      = (float*)d_out;

    const size_t lds_bytes = 2 * PLANE;  // 81920 B -> 2 WGs/CU
    (void)hipFuncSetAttribute((const void*)pinn_mfma,
                              hipFuncAttributeMaxDynamicSharedMemorySize, (int)lds_bytes);

    hipLaunchKernelGGL(prep_w, dim3(512), dim3(64), 0, stream, W_h, whi);
    hipLaunchKernelGGL(pinn_mfma, dim3(NWG), dim3(512), lds_bytes, stream,
                       X, W_in, b_in, b_h, W_out, whi, partials);
    hipLaunchKernelGGL(pinn_reduce_kernel, dim3(1), dim3(256), 0, stream,
                       partials, out);
}

// Round 14
// 316.545 us; speedup vs baseline: 1.8015x; 1.1655x over previous
//
#include <hip/hip_runtime.h>
#include <hip/hip_bf16.h>

typedef __attribute__((ext_vector_type(8)))  short short8;
typedef __attribute__((ext_vector_type(4)))  float f32x4;
typedef __attribute__((ext_vector_type(16))) float f32x16;

#define HIDDEN   256
#define NLAYERS  4
#define NPTS     131072
#define PPW      32
#define NWG      (NPTS / PPW)          // 4096
#define NSTATE   4                     // h, g0, g1, c = gt - (s0+s1)
#define PLANE    65536                 // bytes: 4 states x 16 k-tiles x 1KB

// workspace layout (bytes)
#define WS_PARTIALS   0                          // 4096 doubles = 32 KB
#define WS_WHI        65536                      // 512 KB bf16 W fragments

__device__ __forceinline__ unsigned short f2bf(float f) {
    return __builtin_bit_cast(unsigned short, __float2bfloat16(f));   // HW RNE convert
}
__device__ __forceinline__ float bf2f(unsigned short h) {
    return __uint_as_float(((unsigned)h) << 16);
}
// pack two f32 -> one u32 of 2x bf16 (RNE); __hip_bfloat162 isn't trivially copyable
__device__ __forceinline__ unsigned pack2(float a, float b) {
    __hip_bfloat162 h2 = __float22bfloat162_rn(make_float2(a, b));
    unsigned u;
    __builtin_memcpy(&u, &h2, sizeof(u));
    return u;
}
__device__ __forceinline__ float fast_tanh(float z) {
    // tanh(z) = 1 - 2/(exp(2z)+1): exact at both saturations, no NaN
    float e = __expf(2.f * z);
    return 1.f - __fdividef(2.f, e + 1.f);
}

// ---------------- weight prep: W_h -> bf16, 32x32x16-A fragments ----------------
// Fragment (layer, jt, kt): lane l holds W[k][j] for j = jt*32 + (l&31),
// k = kt*16 + (l>>5)*8 + e (e=0..7). 1 KB per fragment.
__global__ void prep_w(const float* __restrict__ Wh, unsigned short* __restrict__ whi)
{
    int b    = blockIdx.x;               // 512 = 4 layers x 8 jt x 16 kt
    int lay  = b >> 7;
    int jt   = (b >> 4) & 7;
    int kt   = b & 15;
    int lane = threadIdx.x;              // 64
    int j    = jt * 32 + (lane & 31);
    int k0   = kt * 16 + (lane >> 5) * 8;
    const float* W = Wh + lay * 65536;
    int base = ((lay * 8 + jt) * 16 + kt) * 512 + lane * 8;  // ushort units
#pragma unroll
    for (int e = 0; e < 8; ++e)
        whi[base + e] = f2bf(W[(k0 + e) * HIDDEN + j]);
}

// ---------------- fused PINN kernel: 512 thr (8 waves), 64 KB LDS, 2 WGs/CU ----------------
// Single in-place bf16 state plane, 32x32x16 MFMA, 4 jet channels:
//   tile (s, kt) at byte (s*16+kt)*1024 (kt = k>>4, 16 tiles/state).
//   element (s, point p, k): byte = (s*16+(k>>4))*1024 + (((k>>3)&1)*32 + p)*16 + (k&7)*2
//   B-operand: lane l -> col(point) = l&31, k = kt*16 + (l>>5)*8 + e.
// Wave wid owns j-tile jt = wid (32 j rows). mfma(W_frag, S_frag) -> D: col = point,
//   row j = jt*32 + 8*(reg>>2) + 4*(lane>>5) + (reg&3)  -> 4 consecutive j per reg-quad.
// c-channel algebra: c = gt - S; GEMM linear => z_c = GEMM(c);
//   c' = td*z_c + 2*a*td*(z_g0^2 + z_g1^2)   (since -m2 = 2*a*td)
// Two barriers per layer (in-place plane: read -> WAR -> write).
__global__ __launch_bounds__(512, 4)
void pinn_mfma(const float* __restrict__ X,
               const float* __restrict__ W_in, const float* __restrict__ b_in,
               const float* __restrict__ b_h,  const float* __restrict__ W_out,
               const unsigned short* __restrict__ whi,
               double* __restrict__ partials)
{
    extern __shared__ char lds[];
    float*  red = (float*)lds;                // aliases s=0 tiles 0..1 (dead in output phase)
    double* sq  = (double*)(lds + 2048);      // aliases s=0 tile 2: 32 doubles

    const int tid  = threadIdx.x;
    const int lane = tid & 63;
    const int swid = __builtin_amdgcn_readfirstlane(tid >> 6);   // wave id = j-tile, SGPR
    const int h    = lane >> 5;          // k-half / row-half selector
    const int wg   = blockIdx.x;
    const int pt0  = wg * PPW;

    // ---- input layer: thread (p = tid&31, jseg = tid>>5) covers 16 j (4 quads) ----
    {
        const int p    = tid & 31;
        const int jseg = tid >> 5;               // 0..15
        const float* xp = X + (pt0 + p) * 3;
        const float x0 = xp[0], x1 = xp[1], x2 = xp[2];
#pragma unroll
        for (int qq = 0; qq < 4; ++qq) {
            const int j0 = jseg * 16 + qq * 4;
            const f32x4 w0 = *(const f32x4*)(W_in + j0);
            const f32x4 w1 = *(const f32x4*)(W_in + HIDDEN + j0);
            const f32x4 w2 = *(const f32x4*)(W_in + 2 * HIDDEN + j0);
            const f32x4 bq = *(const f32x4*)(b_in + j0);
            float o[NSTATE][4];
#pragma unroll
            for (int r = 0; r < 4; ++r) {
                float z  = fmaf(x0, w0[r], fmaf(x1, w1[r], fmaf(x2, w2[r], bq[r])));
                float a  = fast_tanh(z);
                float td = 1.f - a * a;
                float t2 = 2.f * a * td;         // = -m2
                float sw = fmaf(w0[r], w0[r], w1[r] * w1[r]);
                o[0][r] = a;
                o[1][r] = td * w0[r];
                o[2][r] = td * w1[r];
                o[3][r] = fmaf(td, w2[r], t2 * sw);   // c0 = gt0 - S0
            }
            const int sub = (((j0 >> 3) & 1) * 32 + p) * 16 + (j0 & 7) * 2;
#pragma unroll
            for (int s = 0; s < NSTATE; ++s) {
                uint2 wv = { pack2(o[s][0], o[s][1]), pack2(o[s][2], o[s][3]) };
                *(uint2*)(lds + (s * 16 + (j0 >> 4)) * 1024 + sub) = wv;
            }
        }
    }
    __syncthreads();

    // ---- hidden layers: single-product 32x32x16 MFMA, bf16 W and states, in-place ----
#pragma unroll 1
    for (int l = 0; l < NLAYERS; ++l) {
        const unsigned short* wbh = whi + ((l * 8 + swid) * 16) * 512 + lane * 8;
        const char* sbase = lds + lane * 16;

        f32x16 acc[NSTATE];
#pragma unroll
        for (int s = 0; s < NSTATE; ++s)
            acc[s] = (f32x16){0.f,0.f,0.f,0.f,0.f,0.f,0.f,0.f,0.f,0.f,0.f,0.f,0.f,0.f,0.f,0.f};

#pragma unroll 2
        for (int kt = 0; kt < 16; ++kt) {
            short8 wh = *(const short8*)(wbh + kt * 512);
            short8 sh_[NSTATE];
#pragma unroll
            for (int s = 0; s < NSTATE; ++s)
                sh_[s] = *(const short8*)(sbase + (s * 16 + kt) * 1024);

            __builtin_amdgcn_s_setprio(1);
#pragma unroll
            for (int s = 0; s < NSTATE; ++s)
                acc[s] = __builtin_amdgcn_mfma_f32_32x32x16_bf16(wh, sh_[s], acc[s], 0, 0, 0);
            __builtin_amdgcn_s_setprio(0);
        }

        __syncthreads();   // all GEMM reads done before in-place overwrite

        // tanh jet chain; reg-quad rq -> 4 consecutive j; packed b64 writes
#pragma unroll
        for (int rq = 0; rq < 4; ++rq) {
            const int j0 = swid * 32 + 8 * rq + 4 * h;
            const f32x4 bq = *(const f32x4*)(b_h + l * HIDDEN + j0);
            float o[NSTATE][4];
#pragma unroll
            for (int rr = 0; rr < 4; ++rr) {
                const int r = rq * 4 + rr;
                float z0 = acc[0][r] + bq[rr];
                float z1 = acc[1][r], z2 = acc[2][r], zc = acc[3][r];
                float a  = fast_tanh(z0);
                float td = 1.f - a * a;
                float t2 = 2.f * a * td;         // = -m2
                o[0][rr] = a;
                o[1][rr] = td * z1;
                o[2][rr] = td * z2;
                o[3][rr] = fmaf(td, zc, t2 * fmaf(z1, z1, z2 * z2));   // c'
            }
            const int sub = ((rq & 1) * 32 + (lane & 31)) * 16 + 8 * h;
            const int ktj = swid * 2 + (rq >> 1);
            const int sLo = (l < NLAYERS - 1) ? 0 : 3;   // last layer: only c live
#pragma unroll
            for (int s = 0; s < NSTATE; ++s) {
                if (s < sLo) continue;
                uint2 wv = { pack2(o[s][0], o[s][1]), pack2(o[s][2], o[s][3]) };
                *(uint2*)(lds + (s * 16 + ktj) * 1024 + sub) = wv;
            }
        }
        __syncthreads();   // writes visible before next layer's reads
    }

    // ---- output: residual_p = sum_j W_out[j] * c; reads s=3 tiles only ----
    {
        const int p    = tid & 31;
        const int jseg = tid >> 5;          // 0..15
        float sum = 0.f;
#pragma unroll
        for (int qq = 0; qq < 4; ++qq) {
            const int j0  = jseg * 16 + qq * 4;
            const int sub = (((j0 >> 3) & 1) * 32 + p) * 16 + (j0 & 7) * 2;
            uint2 cv = *(uint2*)(lds + (3 * 16 + (j0 >> 4)) * 1024 + sub);
            f32x4 wo = *(const f32x4*)(W_out + j0);
            sum = fmaf(wo[0], bf2f((unsigned short)(cv.x & 0xFFFF)), sum);
            sum = fmaf(wo[1], bf2f((unsigned short)(cv.x >> 16)),    sum);
            sum = fmaf(wo[2], bf2f((unsigned short)(cv.y & 0xFFFF)), sum);
            sum = fmaf(wo[3], bf2f((unsigned short)(cv.y >> 16)),    sum);
        }
        red[jseg * 32 + p] = sum;           // red aliases s=0 tiles: disjoint from s=3 reads
    }
    __syncthreads();
    if (tid < PPW) {
        float s = 0.f;
        for (int g = 0; g < 16; ++g) s += red[g * 32 + tid];   // fixed order
        double d = (double)s;
        sq[tid] = d * d;
    }
    __syncthreads();
    if (tid == 0) {
        double tot = 0.0;
        for (int p = 0; p < PPW; ++p) tot += sq[p];            // fixed order
        partials[wg] = tot;
    }
}

__global__ void pinn_reduce_kernel(const double* __restrict__ partials, float* __restrict__ out)
{
    __shared__ double sh[256];
    double t = 0.0;
    for (int i = 0; i < NWG / 256; ++i) t += partials[threadIdx.x * (NWG / 256) + i]; // fixed order
    sh[threadIdx.x] = t;
    __syncthreads();
    for (int ofs = 128; ofs > 0; ofs >>= 1) {
        if ((int)threadIdx.x < ofs) sh[threadIdx.x] += sh[threadIdx.x + ofs];
        __syncthreads();
    }
    if (threadIdx.x == 0) {
        out[0] = (float)(sh[0] / (double)NPTS);  // pde_loss
        out[1] = 0.f;                            // ode_loss
    }
}

extern "C" void kernel_launch(void* const* d_in, const int* in_sizes, int n_in,
                              void* d_out, int out_size, void* d_ws, size_t ws_size,
                              hipStream_t stream)
{
    const float* X     = (const float*)d_in[0];
    const float* W_in  = (const float*)d_in[1];
    const float* b_in  = (const float*)d_in[2];
    const float* W_h   = (const float*)d_in[3];
    const float* b_h   = (const float*)d_in[4];
    const float* W_out = (const float*)d_in[5];
    // d_in[6] = b_out: constant output offset, zero derivative -> unused

    double*         partials = (double*)((char*)d_ws + WS_PARTIALS);
    unsigned short* whi      = (unsigned short*)((char*)d_ws + WS_WHI);
    float*          out      = (float*)d_out;

    const size_t lds_bytes = PLANE;      // 65536 B -> 2 WGs/CU
    (void)hipFuncSetAttribute((const void*)pinn_mfma,
                              hipFuncAttributeMaxDynamicSharedMemorySize, (int)lds_bytes);

    hipLaunchKernelGGL(prep_w, dim3(512), dim3(64), 0, stream, W_h, whi);
    hipLaunchKernelGGL(pinn_mfma, dim3(NWG), dim3(512), lds_bytes, stream,
                       X, W_in, b_in, b_h, W_out, whi, partials);
    hipLaunchKernelGGL(pinn_reduce_kernel, dim3(1), dim3(256), 0, stream,
                       partials, out);
}